// Round 5
// baseline (994.154 us; speedup 1.0000x reference)
//
#include <hip/hip_runtime.h>
#include <stdint.h>

#define B_   2
#define S_   2048
#define H_   2048
#define NH_  16
#define NKV_ 4
#define HD_  128

typedef short bf16x8 __attribute__((ext_vector_type(8)));
typedef float f32x4  __attribute__((ext_vector_type(4)));

__device__ __forceinline__ float b2f(unsigned short u) {
  union { unsigned int u; float f; } v; v.u = ((unsigned int)u) << 16; return v.f;
}
__device__ __forceinline__ unsigned short f2b(float f) {
  union { float f; unsigned int u; } v; v.f = f;
  unsigned int u = v.u;
  unsigned int r = (u + 0x7FFFu + ((u >> 16) & 1u)) >> 16;
  return (unsigned short)r;
}
__device__ __forceinline__ uint4 pack8(const float4& a, const float4& b) {
  uint4 r;
  r.x = (unsigned)f2b(a.x) | ((unsigned)f2b(a.y) << 16);
  r.y = (unsigned)f2b(a.z) | ((unsigned)f2b(a.w) << 16);
  r.z = (unsigned)f2b(b.x) | ((unsigned)f2b(b.y) << 16);
  r.w = (unsigned)f2b(b.z) | ((unsigned)f2b(b.w) << 16);
  return r;
}

// ---------------------------------------------------------------------------
// C[M,N] = A[M,K] @ B[N,K]^T  (f32 accumulate). A/B: f32 (converted to bf16 at
// staging) or bf16 per immediate flags. C: f32 or bf16 per cF32.
// 128x128 tile, BK=64, 256 threads = 4 waves in 2x2, each wave 64x64 (4x4 frags)
// ---------------------------------------------------------------------------
__global__ __launch_bounds__(256, 2) void gemm_bt(
    const void* __restrict__ A, const void* __restrict__ Bm,
    void* __restrict__ C, int M, int N, int K,
    int aBf16, int bBf16, int cF32)
{
  __shared__ unsigned short As[128 * 72];   // +8 pad: 2-way bank alias only (free)
  __shared__ unsigned short Bs[128 * 72];

  const int tid    = threadIdx.x;
  const int lane   = tid & 63;
  const int wid    = tid >> 6;
  const int wrow   = wid >> 1;
  const int wcol   = wid & 1;
  const int lane15 = lane & 15;
  const int quad   = lane >> 4;
  const int rowBase = blockIdx.y * 128;
  const int colBase = blockIdx.x * 128;

  const f32x4 zero = {0.f, 0.f, 0.f, 0.f};
  f32x4 acc[4][4];
#pragma unroll
  for (int i = 0; i < 4; i++)
#pragma unroll
    for (int j = 0; j < 4; j++) acc[i][j] = zero;

  const int r0 = tid >> 3;  // 0..31
  const int c8 = tid & 7;   // 0..7 (8-element chunk within 64-wide K slab)

  for (int kb = 0; kb < K; kb += 64) {
    uint4 av[4], bv[4];
    if (aBf16) {
      const unsigned short* Ab = (const unsigned short*)A;
#pragma unroll
      for (int p = 0; p < 4; p++) {
        int r = r0 + 32 * p;
        av[p] = *reinterpret_cast<const uint4*>(Ab + (size_t)(rowBase + r) * K + kb + c8 * 8);
      }
    } else {
      const float* Af = (const float*)A;
#pragma unroll
      for (int p = 0; p < 4; p++) {
        int r = r0 + 32 * p;
        const float* pA = Af + (size_t)(rowBase + r) * K + kb + c8 * 8;
        float4 f0 = *reinterpret_cast<const float4*>(pA);
        float4 f1 = *reinterpret_cast<const float4*>(pA + 4);
        av[p] = pack8(f0, f1);
      }
    }
    if (bBf16) {
      const unsigned short* Bb = (const unsigned short*)Bm;
#pragma unroll
      for (int p = 0; p < 4; p++) {
        int r = r0 + 32 * p;
        bv[p] = *reinterpret_cast<const uint4*>(Bb + (size_t)(colBase + r) * K + kb + c8 * 8);
      }
    } else {
      const float* Bf = (const float*)Bm;
#pragma unroll
      for (int p = 0; p < 4; p++) {
        int r = r0 + 32 * p;
        const float* pB = Bf + (size_t)(colBase + r) * K + kb + c8 * 8;
        float4 f0 = *reinterpret_cast<const float4*>(pB);
        float4 f1 = *reinterpret_cast<const float4*>(pB + 4);
        bv[p] = pack8(f0, f1);
      }
    }
    __syncthreads();
#pragma unroll
    for (int p = 0; p < 4; p++) {
      int r = r0 + 32 * p;
      *reinterpret_cast<uint4*>(As + r * 72 + c8 * 8) = av[p];
      *reinterpret_cast<uint4*>(Bs + r * 72 + c8 * 8) = bv[p];
    }
    __syncthreads();
#pragma unroll
    for (int kc = 0; kc < 2; kc++) {
      bf16x8 af[4], bf[4];
#pragma unroll
      for (int g = 0; g < 4; g++) {
        af[g] = *reinterpret_cast<const bf16x8*>(As + (wrow * 64 + g * 16 + lane15) * 72 + kc * 32 + quad * 8);
        bf[g] = *reinterpret_cast<const bf16x8*>(Bs + (wcol * 64 + g * 16 + lane15) * 72 + kc * 32 + quad * 8);
      }
#pragma unroll
      for (int i = 0; i < 4; i++)
#pragma unroll
        for (int j = 0; j < 4; j++)
          acc[i][j] = __builtin_amdgcn_mfma_f32_16x16x32_bf16(af[i], bf[j], acc[i][j], 0, 0, 0);
    }
  }

  if (cF32) {
    float* Cf = (float*)C;
#pragma unroll
    for (int i = 0; i < 4; i++) {
      int row = rowBase + wrow * 64 + i * 16 + quad * 4;
#pragma unroll
      for (int j = 0; j < 4; j++) {
        int col = colBase + wcol * 64 + j * 16 + lane15;
#pragma unroll
        for (int rr = 0; rr < 4; rr++)
          Cf[(size_t)(row + rr) * N + col] = acc[i][j][rr];
      }
    }
  } else {
    unsigned short* Cb = (unsigned short*)C;
#pragma unroll
    for (int i = 0; i < 4; i++) {
      int row = rowBase + wrow * 64 + i * 16 + quad * 4;
#pragma unroll
      for (int j = 0; j < 4; j++) {
        int col = colBase + wcol * 64 + j * 16 + lane15;
#pragma unroll
        for (int rr = 0; rr < 4; rr++)
          Cb[(size_t)(row + rr) * N + col] = f2b(acc[i][j][rr]);
      }
    }
  }
}

// ---------------------------------------------------------------------------
// RoPE in-place on bf16 Q [B*S, NH*HD] and K [B*S, NKV*HD]; one thread per
// (d, d+64) pair. cos/sin tables are f32 and duplicate across halves.
// ---------------------------------------------------------------------------
__global__ void rope_k(unsigned short* __restrict__ Qb, unsigned short* __restrict__ Kb,
                       const float* __restrict__ cosT, const float* __restrict__ sinT)
{
  const int per_tok = (NH_ + NKV_) * 64;  // 1280
  int idx = blockIdx.x * blockDim.x + threadIdx.x;
  int t = idx / per_tok;
  int r = idx - t * per_tok;
  if (t >= B_ * S_) return;
  int s = t & (S_ - 1);
  unsigned short* base;
  int d;
  if (r < NH_ * 64) {
    int h = r >> 6; d = r & 63;
    base = Qb + (size_t)t * (NH_ * HD_) + h * HD_ + d;
  } else {
    int rk = r - NH_ * 64;
    int h = rk >> 6; d = rk & 63;
    base = Kb + (size_t)t * (NKV_ * HD_) + h * HD_ + d;
  }
  float c  = cosT[s * HD_ + d];
  float sn = sinT[s * HD_ + d];
  float x0 = b2f(base[0]);
  float x1 = b2f(base[64]);
  base[0]  = f2b(x0 * c - x1 * sn);
  base[64] = f2b(x1 * c + x0 * sn);
}

// ---------------------------------------------------------------------------
// Flash attention (causal, GQA), all-bf16 buffers. Block = (b, h, 64-row Q
// tile), 4 waves x 16 rows. 32-key tiles in LDS. Online softmax, f32 state.
// O aliases Q (in-place): each block's write region equals its own read region.
// ---------------------------------------------------------------------------
__global__ __launch_bounds__(256, 2) void attn(
    const unsigned short* Q, const unsigned short* __restrict__ Kc,
    const unsigned short* __restrict__ Vc, unsigned short* O)
{
  __shared__ unsigned short Ks[32 * 136];      // keys x dims, +8 pad
  __shared__ unsigned short Vs[128 * 40];      // dims x keys (transposed), +8 pad
  __shared__ unsigned short Ps[4][16 * 40];    // per-wave P tile, +8 pad

  const int tid    = threadIdx.x;
  const int lane   = tid & 63;
  const int w      = tid >> 6;
  const int lane15 = lane & 15;
  const int quad   = lane >> 4;
  const int qbase  = blockIdx.x * 64;
  const int h      = blockIdx.y;
  const int b      = blockIdx.z;
  const int kv     = h >> 2;

  // Q fragments (A-layout): row = lane15 within wave tile, k = kc*32 + quad*8 + j
  bf16x8 qf[4];
  {
    const unsigned short* qp = Q + (size_t)(b * S_ + qbase + w * 16 + lane15) * (NH_ * HD_) + h * HD_ + quad * 8;
#pragma unroll
    for (int kc = 0; kc < 4; kc++)
      qf[kc] = *reinterpret_cast<const bf16x8*>(qp + kc * 32);
  }

  const f32x4 zero = {0.f, 0.f, 0.f, 0.f};
  f32x4 ctx[8];
#pragma unroll
  for (int ng = 0; ng < 8; ng++) ctx[ng] = zero;
  float m_i[4], l_i[4];
#pragma unroll
  for (int rr = 0; rr < 4; rr++) { m_i[rr] = -1.0e30f; l_i[rr] = 0.f; }

  const int nkt  = qbase / 32 + 2;
  const int kr   = tid >> 4;   // staging: key row within 16-row half-tile
  const int kc16 = tid & 15;   // staging: 8-elem chunk = dims kc16*8 .. +7

  for (int kt = 0; kt < nkt; kt++) {
    __syncthreads();
    // Stage K[32x128] and V^T[128x32]: 2 passes x 16 keys x 16 chunks
#pragma unroll
    for (int p = 0; p < 2; p++) {
      int krow = p * 16 + kr;
      int key  = kt * 32 + krow;
      uint4 kvv = *reinterpret_cast<const uint4*>(Kc + (size_t)(b * S_ + key) * (NKV_ * HD_) + kv * HD_ + kc16 * 8);
      *reinterpret_cast<uint4*>(Ks + krow * 136 + kc16 * 8) = kvv;
      uint4 vv = *reinterpret_cast<const uint4*>(Vc + (size_t)(b * S_ + key) * (NKV_ * HD_) + kv * HD_ + kc16 * 8);
      const unsigned short* ve = reinterpret_cast<const unsigned short*>(&vv);
#pragma unroll
      for (int j = 0; j < 8; j++)
        Vs[(kc16 * 8 + j) * 40 + krow] = ve[j];
    }
    __syncthreads();

    // scores: S[16 x 32] = Q[16x128] @ K^T
    f32x4 sc[2];
    sc[0] = zero; sc[1] = zero;
#pragma unroll
    for (int cg = 0; cg < 2; cg++)
#pragma unroll
      for (int kc = 0; kc < 4; kc++) {
        bf16x8 kf = *reinterpret_cast<const bf16x8*>(Ks + (cg * 16 + lane15) * 136 + kc * 32 + quad * 8);
        sc[cg] = __builtin_amdgcn_mfma_f32_16x16x32_bf16(qf[kc], kf, sc[cg], 0, 0, 0);
      }

    // scale + causal mask
    const float scale = 0.08838834764831845f;  // 1/sqrt(128)
#pragma unroll
    for (int cg = 0; cg < 2; cg++) {
      int key = kt * 32 + cg * 16 + lane15;
#pragma unroll
      for (int rr = 0; rr < 4; rr++) {
        int qrow = qbase + w * 16 + quad * 4 + rr;
        float v = sc[cg][rr] * scale;
        sc[cg][rr] = (key <= qrow) ? v : -1.0e9f;
      }
    }

    // online softmax (row = quad*4+rr; 16 lanes of the quad hold the 16 cols)
    float pv0[4], pv1[4];
#pragma unroll
    for (int rr = 0; rr < 4; rr++) {
      float tm = fmaxf(sc[0][rr], sc[1][rr]);
      tm = fmaxf(tm, __shfl_xor(tm, 1));
      tm = fmaxf(tm, __shfl_xor(tm, 2));
      tm = fmaxf(tm, __shfl_xor(tm, 4));
      tm = fmaxf(tm, __shfl_xor(tm, 8));
      float mn = fmaxf(m_i[rr], tm);
      float alpha = __expf(m_i[rr] - mn);
      m_i[rr] = mn;
      float p0 = __expf(sc[0][rr] - mn);
      float p1 = __expf(sc[1][rr] - mn);
      float rs = p0 + p1;
      rs += __shfl_xor(rs, 1);
      rs += __shfl_xor(rs, 2);
      rs += __shfl_xor(rs, 4);
      rs += __shfl_xor(rs, 8);
      l_i[rr] = l_i[rr] * alpha + rs;
      pv0[rr] = p0; pv1[rr] = p1;
#pragma unroll
      for (int ng = 0; ng < 8; ng++) ctx[ng][rr] *= alpha;
    }

    // P: C-layout -> LDS -> A-layout (per-wave buffer; block barrier)
#pragma unroll
    for (int rr = 0; rr < 4; rr++) {
      Ps[w][(quad * 4 + rr) * 40 + lane15]      = f2b(pv0[rr]);
      Ps[w][(quad * 4 + rr) * 40 + 16 + lane15] = f2b(pv1[rr]);
    }
    __syncthreads();
    bf16x8 pf = *reinterpret_cast<const bf16x8*>(&Ps[w][lane15 * 40 + quad * 8]);

    // ctx[16x128] += P[16x32] @ V[32x128]
#pragma unroll
    for (int ng = 0; ng < 8; ng++) {
      bf16x8 vf = *reinterpret_cast<const bf16x8*>(Vs + (ng * 16 + lane15) * 40 + quad * 8);
      ctx[ng] = __builtin_amdgcn_mfma_f32_16x16x32_bf16(pf, vf, ctx[ng], 0, 0, 0);
    }
  }

  float inv[4];
#pragma unroll
  for (int rr = 0; rr < 4; rr++) inv[rr] = 1.0f / l_i[rr];
  const int qrow = qbase + w * 16 + quad * 4;
#pragma unroll
  for (int ng = 0; ng < 8; ng++)
#pragma unroll
    for (int rr = 0; rr < 4; rr++)
      O[(size_t)(b * S_ + qrow + rr) * (NH_ * HD_) + h * HD_ + ng * 16 + lane15] = f2b(ctx[ng][rr] * inv[rr]);
}

// ---------------------------------------------------------------------------
// Memory plan: Qb (bf16, 16 MB) in d_ws (guarded). K/V projections (bf16, 4 MB
// each) staged at the head of d_out (f32 buffer, 33.5 MB) — consumed by attn
// before the final GEMM overwrites out; launches are stream-serialized.
// attn writes ctx in-place over Qb (per-block regions disjoint).
// ---------------------------------------------------------------------------
extern "C" void kernel_launch(void* const* d_in, const int* in_sizes, int n_in,
                              void* d_out, int out_size, void* d_ws, size_t ws_size,
                              hipStream_t stream) {
  const float* x    = (const float*)d_in[0];
  const float* Wq   = (const float*)d_in[1];
  const float* Wk   = (const float*)d_in[2];
  const float* Wv   = (const float*)d_in[3];
  const float* Wo   = (const float*)d_in[4];
  const float* cosT = (const float*)d_in[5];
  const float* sinT = (const float*)d_in[6];
  // d_in[7] = mask: causal, applied analytically
  float* out = (float*)d_out;

  const int M = B_ * S_;  // 4096
  const size_t qbytes = (size_t)M * NH_ * HD_ * 2;  // 16 MB
  if (ws_size < qbytes + 256) return;               // guard (proven satisfied)

  unsigned short* Qb = (unsigned short*)d_ws;              // [M, 2048] bf16
  unsigned short* Kb = (unsigned short*)d_out;             // [M, 512] bf16 (head of out)
  unsigned short* Vb = Kb + (size_t)M * NKV_ * HD_;        // [M, 512] bf16

  dim3 blk(256);
  gemm_bt<<<dim3((NKV_ * HD_) / 128, M / 128), blk, 0, stream>>>(x, Wk, Kb, M, NKV_ * HD_, H_, 0, 0, 0);
  gemm_bt<<<dim3((NKV_ * HD_) / 128, M / 128), blk, 0, stream>>>(x, Wv, Vb, M, NKV_ * HD_, H_, 0, 0, 0);
  gemm_bt<<<dim3((NH_ * HD_) / 128, M / 128), blk, 0, stream>>>(x, Wq, Qb, M, NH_ * HD_, H_, 0, 0, 0);

  int rope_threads = B_ * S_ * (NH_ + NKV_) * 64;
  rope_k<<<dim3((rope_threads + 255) / 256), blk, 0, stream>>>(Qb, Kb, cosT, sinT);

  attn<<<dim3(S_ / 64, NH_, B_), blk, 0, stream>>>(Qb, Kb, Vb, Qb);  // ctx in-place over Qb

  gemm_bt<<<dim3(H_ / 128, M / 128), blk, 0, stream>>>(Qb, Wo, out, M, H_, NH_ * HD_, 1, 0, 1);
}

// Round 6
// 757.792 us; speedup vs baseline: 1.3119x; 1.3119x over previous
//
#include <hip/hip_runtime.h>
#include <stdint.h>

#define B_   2
#define S_   2048
#define H_   2048
#define NH_  16
#define NKV_ 4
#define HD_  128
#define M_   (B_ * S_)   // 4096

typedef short bf16x8 __attribute__((ext_vector_type(8)));
typedef float f32x4  __attribute__((ext_vector_type(4)));

__device__ __forceinline__ float b2f(unsigned short u) {
  union { unsigned int u; float f; } v; v.u = ((unsigned int)u) << 16; return v.f;
}
__device__ __forceinline__ unsigned short f2b(float f) {
  union { float f; unsigned int u; } v; v.f = f;
  unsigned int u = v.u;
  unsigned int r = (u + 0x7FFFu + ((u >> 16) & 1u)) >> 16;
  return (unsigned short)r;
}
__device__ __forceinline__ uint4 pack8(const float4& a, const float4& b) {
  uint4 r;
  r.x = (unsigned)f2b(a.x) | ((unsigned)f2b(a.y) << 16);
  r.y = (unsigned)f2b(a.z) | ((unsigned)f2b(a.w) << 16);
  r.z = (unsigned)f2b(b.x) | ((unsigned)f2b(b.y) << 16);
  r.w = (unsigned)f2b(b.z) | ((unsigned)f2b(b.w) << 16);
  return r;
}

// ---------------------------------------------------------------------------
// GEMM C[M,N] = A[M,K] @ B[N,K]^T, f32 accumulate. OPROJ: A bf16, C f32;
// else A f32 (packed to bf16 at load), C bf16. B always f32.
// 128x128 tile, BK=64, 4 waves 2x2, register prefetch of next K-slab.
// Dual-output: blockIdx.x < nxHalf -> (B0,C0) else (B1,C1).
// ---------------------------------------------------------------------------
template<bool OPROJ>
__global__ __launch_bounds__(256, 3) void gemm_k(
    const void* __restrict__ A, const float* __restrict__ B0, const float* __restrict__ B1,
    void* __restrict__ C0, void* __restrict__ C1, int N, int K, int nxHalf)
{
  __shared__ unsigned short As[128 * 72];
  __shared__ unsigned short Bs[128 * 72];

  const float* Bm; void* Cm; int colBase;
  if ((int)blockIdx.x < nxHalf) { Bm = B0; Cm = C0; colBase = blockIdx.x * 128; }
  else                          { Bm = B1; Cm = C1; colBase = (blockIdx.x - nxHalf) * 128; }
  const int rowBase = blockIdx.y * 128;

  const int tid    = threadIdx.x;
  const int lane   = tid & 63;
  const int wid    = tid >> 6;
  const int wrow   = wid >> 1;
  const int wcol   = wid & 1;
  const int lane15 = lane & 15;
  const int quad   = lane >> 4;

  const f32x4 zero = {0.f, 0.f, 0.f, 0.f};
  f32x4 acc[4][4];
#pragma unroll
  for (int i = 0; i < 4; i++)
#pragma unroll
    for (int j = 0; j < 4; j++) acc[i][j] = zero;

  const int r0 = tid >> 3;  // 0..31
  const int c8 = tid & 7;   // 0..7

  uint4 av[4], bv[4];
  // prefetch kb = 0
#pragma unroll
  for (int p = 0; p < 4; p++) {
    int r = r0 + 32 * p;
    if (OPROJ) {
      av[p] = *reinterpret_cast<const uint4*>((const unsigned short*)A + (size_t)(rowBase + r) * K + c8 * 8);
    } else {
      const float* pA = (const float*)A + (size_t)(rowBase + r) * K + c8 * 8;
      av[p] = pack8(*reinterpret_cast<const float4*>(pA), *reinterpret_cast<const float4*>(pA + 4));
    }
    const float* pB = Bm + (size_t)(colBase + r) * K + c8 * 8;
    bv[p] = pack8(*reinterpret_cast<const float4*>(pB), *reinterpret_cast<const float4*>(pB + 4));
  }

  for (int kb = 0; kb < K; kb += 64) {
    __syncthreads();
#pragma unroll
    for (int p = 0; p < 4; p++) {
      int r = r0 + 32 * p;
      *reinterpret_cast<uint4*>(As + r * 72 + c8 * 8) = av[p];
      *reinterpret_cast<uint4*>(Bs + r * 72 + c8 * 8) = bv[p];
    }
    __syncthreads();
    const int kn = kb + 64;
    if (kn < K) {
#pragma unroll
      for (int p = 0; p < 4; p++) {
        int r = r0 + 32 * p;
        if (OPROJ) {
          av[p] = *reinterpret_cast<const uint4*>((const unsigned short*)A + (size_t)(rowBase + r) * K + kn + c8 * 8);
        } else {
          const float* pA = (const float*)A + (size_t)(rowBase + r) * K + kn + c8 * 8;
          av[p] = pack8(*reinterpret_cast<const float4*>(pA), *reinterpret_cast<const float4*>(pA + 4));
        }
        const float* pB = Bm + (size_t)(colBase + r) * K + kn + c8 * 8;
        bv[p] = pack8(*reinterpret_cast<const float4*>(pB), *reinterpret_cast<const float4*>(pB + 4));
      }
    }
#pragma unroll
    for (int kc = 0; kc < 2; kc++) {
      bf16x8 af[4], bf[4];
#pragma unroll
      for (int g = 0; g < 4; g++) {
        af[g] = *reinterpret_cast<const bf16x8*>(As + (wrow * 64 + g * 16 + lane15) * 72 + kc * 32 + quad * 8);
        bf[g] = *reinterpret_cast<const bf16x8*>(Bs + (wcol * 64 + g * 16 + lane15) * 72 + kc * 32 + quad * 8);
      }
#pragma unroll
      for (int i = 0; i < 4; i++)
#pragma unroll
        for (int j = 0; j < 4; j++)
          acc[i][j] = __builtin_amdgcn_mfma_f32_16x16x32_bf16(af[i], bf[j], acc[i][j], 0, 0, 0);
    }
  }

  if (OPROJ) {
    float* Cf = (float*)Cm;
#pragma unroll
    for (int i = 0; i < 4; i++) {
      int row = rowBase + wrow * 64 + i * 16 + quad * 4;
#pragma unroll
      for (int j = 0; j < 4; j++) {
        int col = colBase + wcol * 64 + j * 16 + lane15;
#pragma unroll
        for (int rr = 0; rr < 4; rr++)
          Cf[(size_t)(row + rr) * N + col] = acc[i][j][rr];
      }
    }
  } else {
    unsigned short* Cb = (unsigned short*)Cm;
#pragma unroll
    for (int i = 0; i < 4; i++) {
      int row = rowBase + wrow * 64 + i * 16 + quad * 4;
#pragma unroll
      for (int j = 0; j < 4; j++) {
        int col = colBase + wcol * 64 + j * 16 + lane15;
#pragma unroll
        for (int rr = 0; rr < 4; rr++)
          Cb[(size_t)(row + rr) * N + col] = f2b(acc[i][j][rr]);
      }
    }
  }
}

// ---------------------------------------------------------------------------
// RoPE in-place on bf16 Q [M, 2048] and K [M, 512]; cos/sin f32.
// ---------------------------------------------------------------------------
__global__ void rope_k(unsigned short* __restrict__ Qb, unsigned short* __restrict__ Kb,
                       const float* __restrict__ cosT, const float* __restrict__ sinT)
{
  const int per_tok = (NH_ + NKV_) * 64;  // 1280
  int idx = blockIdx.x * blockDim.x + threadIdx.x;
  int t = idx / per_tok;
  int r = idx - t * per_tok;
  if (t >= M_) return;
  int s = t & (S_ - 1);
  unsigned short* base;
  int d;
  if (r < NH_ * 64) {
    int h = r >> 6; d = r & 63;
    base = Qb + (size_t)t * (NH_ * HD_) + h * HD_ + d;
  } else {
    int rk = r - NH_ * 64;
    int h = rk >> 6; d = rk & 63;
    base = Kb + (size_t)t * (NKV_ * HD_) + h * HD_ + d;
  }
  float c  = cosT[s * HD_ + d];
  float sn = sinT[s * HD_ + d];
  float x0 = b2f(base[0]);
  float x1 = b2f(base[64]);
  base[0]  = f2b(x0 * c - x1 * sn);
  base[64] = f2b(x1 * c + x0 * sn);
}

// ---------------------------------------------------------------------------
// V transpose: Vb[M,512] (token-major) -> VT[B*512, 2048] (dim-major, key cols).
// 64x64 tiles through LDS. Tiny kernel (8 MB traffic) — conflicts acceptable.
// ---------------------------------------------------------------------------
__global__ void transp_v(const unsigned short* __restrict__ Vb, unsigned short* __restrict__ VT)
{
  __shared__ unsigned short Ls[64 * 72];
  const int t0 = blockIdx.x * 64;   // token tile
  const int d0 = blockIdx.y * 64;   // dim tile (within 512)
  const int tid = threadIdx.x;
  const int r = tid >> 3, c = tid & 7;
#pragma unroll
  for (int p = 0; p < 2; p++)
    *reinterpret_cast<uint4*>(Ls + (r + 32 * p) * 72 + c * 8) =
      *reinterpret_cast<const uint4*>(Vb + (size_t)(t0 + r + 32 * p) * (NKV_ * HD_) + d0 + c * 8);
  __syncthreads();
  const int bq = t0 >> 11, s0 = t0 & (S_ - 1);
#pragma unroll
  for (int p = 0; p < 2; p++) {
    int dl = r + 32 * p;
    unsigned short tmp[8];
#pragma unroll
    for (int j = 0; j < 8; j++) tmp[j] = Ls[(c * 8 + j) * 72 + dl];
    *reinterpret_cast<uint4*>(VT + (size_t)(bq * 512 + d0 + dl) * S_ + s0 + c * 8) =
      *reinterpret_cast<uint4*>(tmp);
  }
}

// ---------------------------------------------------------------------------
// Flash attention (causal, GQA). Block = (b, h, 64-row Q tile), 4 waves x 16
// rows, 64-key tiles, register prefetch of next K/V tile, mask only on the
// diagonal tile, reversed dispatch (longest blocks first).
// O aliases Q in-place (per-block read/write regions coincide & are disjoint).
// ---------------------------------------------------------------------------
__global__ __launch_bounds__(256, 3) void attn(
    const unsigned short* Q, const unsigned short* __restrict__ Kc,
    const unsigned short* __restrict__ VT, unsigned short* O)
{
  __shared__ unsigned short Ks[64 * 136];   // keys x dims (+8 pad)
  __shared__ unsigned short Vs[128 * 72];   // dims x keys (+8 pad)
  __shared__ unsigned short Ps[4][16 * 72]; // per-wave P tile (+8 pad)

  const int tid    = threadIdx.x;
  const int lane   = tid & 63;
  const int w      = tid >> 6;
  const int lane15 = lane & 15;
  const int quad   = lane >> 4;
  const int qt     = (gridDim.x - 1) - blockIdx.x;  // longest first
  const int qbase  = qt * 64;
  const int h      = blockIdx.y;
  const int b      = blockIdx.z;
  const int kvh    = h >> 2;
  const size_t bS  = (size_t)b * S_;

  // Q fragments (A-layout)
  bf16x8 qf[4];
  {
    const unsigned short* qp = Q + (bS + qbase + w * 16 + lane15) * (NH_ * HD_) + h * HD_ + quad * 8;
#pragma unroll
    for (int kc = 0; kc < 4; kc++)
      qf[kc] = *reinterpret_cast<const bf16x8*>(qp + kc * 32);
  }

  const f32x4 zero = {0.f, 0.f, 0.f, 0.f};
  f32x4 ctx[8];
#pragma unroll
  for (int ng = 0; ng < 8; ng++) ctx[ng] = zero;
  float m_i[4], l_i[4];
#pragma unroll
  for (int rr = 0; rr < 4; rr++) { m_i[rr] = -1.0e30f; l_i[rr] = 0.f; }

  const int nkt = qt + 1;
  // staging thread mapping
  const int skr = tid >> 4;   // K: row within 16-row pass (x4 passes = 64 keys)
  const int skc = tid & 15;   // K: 8-dim chunk
  const int svd = tid >> 3;   // V: dim within 32-dim pass (x4 passes = 128)
  const int svc = tid & 7;    // V: 8-key chunk (x8 = 64 keys)
  const unsigned short* Kbase = Kc + bS * (NKV_ * HD_) + kvh * HD_;
  const unsigned short* Vbase = VT + (size_t)(b * 512 + kvh * HD_) * S_;

  uint4 kreg[4], vreg[4];
#pragma unroll
  for (int p = 0; p < 4; p++) {
    kreg[p] = *reinterpret_cast<const uint4*>(Kbase + (size_t)(skr + 16 * p) * (NKV_ * HD_) + skc * 8);
    vreg[p] = *reinterpret_cast<const uint4*>(Vbase + (size_t)(svd + 32 * p) * S_ + svc * 8);
  }

  const float scale = 0.08838834764831845f;  // 1/sqrt(128)

  for (int kt = 0; kt < nkt; kt++) {
    __syncthreads();
#pragma unroll
    for (int p = 0; p < 4; p++) {
      *reinterpret_cast<uint4*>(Ks + (skr + 16 * p) * 136 + skc * 8) = kreg[p];
      *reinterpret_cast<uint4*>(Vs + (svd + 32 * p) * 72 + svc * 8) = vreg[p];
    }
    __syncthreads();
    if (kt + 1 < nkt) {
      const int key0 = (kt + 1) * 64;
#pragma unroll
      for (int p = 0; p < 4; p++) {
        kreg[p] = *reinterpret_cast<const uint4*>(Kbase + (size_t)(key0 + skr + 16 * p) * (NKV_ * HD_) + skc * 8);
        vreg[p] = *reinterpret_cast<const uint4*>(Vbase + (size_t)(svd + 32 * p) * S_ + key0 + svc * 8);
      }
    }

    // scores: S[16 x 64] = Q[16x128] @ K^T
    f32x4 sc[4];
#pragma unroll
    for (int cg = 0; cg < 4; cg++) sc[cg] = zero;
#pragma unroll
    for (int cg = 0; cg < 4; cg++)
#pragma unroll
      for (int kc = 0; kc < 4; kc++) {
        bf16x8 kf = *reinterpret_cast<const bf16x8*>(Ks + (cg * 16 + lane15) * 136 + kc * 32 + quad * 8);
        sc[cg] = __builtin_amdgcn_mfma_f32_16x16x32_bf16(qf[kc], kf, sc[cg], 0, 0, 0);
      }

    if (kt == nkt - 1) {  // diagonal tile: scale + causal mask
#pragma unroll
      for (int cg = 0; cg < 4; cg++) {
        int key = kt * 64 + cg * 16 + lane15;
#pragma unroll
        for (int rr = 0; rr < 4; rr++) {
          int qrow = qbase + w * 16 + quad * 4 + rr;
          float v = sc[cg][rr] * scale;
          sc[cg][rr] = (key <= qrow) ? v : -1.0e9f;
        }
      }
    } else {
#pragma unroll
      for (int cg = 0; cg < 4; cg++)
#pragma unroll
        for (int rr = 0; rr < 4; rr++) sc[cg][rr] *= scale;
    }

    // online softmax; write P tiles (per-wave LDS)
#pragma unroll
    for (int rr = 0; rr < 4; rr++) {
      float tm = fmaxf(fmaxf(sc[0][rr], sc[1][rr]), fmaxf(sc[2][rr], sc[3][rr]));
      tm = fmaxf(tm, __shfl_xor(tm, 1));
      tm = fmaxf(tm, __shfl_xor(tm, 2));
      tm = fmaxf(tm, __shfl_xor(tm, 4));
      tm = fmaxf(tm, __shfl_xor(tm, 8));
      float mn = fmaxf(m_i[rr], tm);
      float alpha = __expf(m_i[rr] - mn);
      m_i[rr] = mn;
      float p0 = __expf(sc[0][rr] - mn);
      float p1 = __expf(sc[1][rr] - mn);
      float p2 = __expf(sc[2][rr] - mn);
      float p3 = __expf(sc[3][rr] - mn);
      float rs = (p0 + p1) + (p2 + p3);
      rs += __shfl_xor(rs, 1);
      rs += __shfl_xor(rs, 2);
      rs += __shfl_xor(rs, 4);
      rs += __shfl_xor(rs, 8);
      l_i[rr] = l_i[rr] * alpha + rs;
      int prow = (quad * 4 + rr) * 72;
      Ps[w][prow + lane15]      = f2b(p0);
      Ps[w][prow + 16 + lane15] = f2b(p1);
      Ps[w][prow + 32 + lane15] = f2b(p2);
      Ps[w][prow + 48 + lane15] = f2b(p3);
#pragma unroll
      for (int ng = 0; ng < 8; ng++) ctx[ng][rr] *= alpha;
    }
    __threadfence_block();  // wave-local LDS RAW ordering for Ps[w]

    bf16x8 pf[2];
#pragma unroll
    for (int kc = 0; kc < 2; kc++)
      pf[kc] = *reinterpret_cast<const bf16x8*>(&Ps[w][lane15 * 72 + kc * 32 + quad * 8]);

    // ctx[16x128] += P[16x64] @ V[64x128]
#pragma unroll
    for (int ng = 0; ng < 8; ng++)
#pragma unroll
      for (int kc = 0; kc < 2; kc++) {
        bf16x8 vf = *reinterpret_cast<const bf16x8*>(Vs + (ng * 16 + lane15) * 72 + kc * 32 + quad * 8);
        ctx[ng] = __builtin_amdgcn_mfma_f32_16x16x32_bf16(pf[kc], vf, ctx[ng], 0, 0, 0);
      }
  }

  float inv[4];
#pragma unroll
  for (int rr = 0; rr < 4; rr++) inv[rr] = 1.0f / l_i[rr];
  const int qrow = qbase + w * 16 + quad * 4;
#pragma unroll
  for (int ng = 0; ng < 8; ng++)
#pragma unroll
    for (int rr = 0; rr < 4; rr++)
      O[(bS + qrow + rr) * (NH_ * HD_) + h * HD_ + ng * 16 + lane15] = f2b(ctx[ng][rr] * inv[rr]);
}

// ---------------------------------------------------------------------------
// Memory plan: Qb (bf16, 16 MB) in d_ws (guarded). Kb/Vb/VT (bf16, 4 MB each)
// at head of d_out (33.5 MB) — all consumed before the final GEMM overwrites
// out; launches stream-serialized. attn writes ctx in-place over Qb.
// ---------------------------------------------------------------------------
extern "C" void kernel_launch(void* const* d_in, const int* in_sizes, int n_in,
                              void* d_out, int out_size, void* d_ws, size_t ws_size,
                              hipStream_t stream) {
  const float* x    = (const float*)d_in[0];
  const float* Wq   = (const float*)d_in[1];
  const float* Wk   = (const float*)d_in[2];
  const float* Wv   = (const float*)d_in[3];
  const float* Wo   = (const float*)d_in[4];
  const float* cosT = (const float*)d_in[5];
  const float* sinT = (const float*)d_in[6];
  // d_in[7] = mask: causal, applied analytically
  float* out = (float*)d_out;

  const size_t qbytes = (size_t)M_ * NH_ * HD_ * 2;  // 16 MB
  if (ws_size < qbytes + 256) return;

  unsigned short* Qb = (unsigned short*)d_ws;            // [M, 2048] bf16
  unsigned short* Kb = (unsigned short*)d_out;           // [M, 512]  bf16
  unsigned short* Vb = Kb + (size_t)M_ * NKV_ * HD_;     // [M, 512]  bf16
  unsigned short* VT = Vb + (size_t)M_ * NKV_ * HD_;     // [B*512, 2048] bf16

  dim3 blk(256);
  // Q projection: N=2048, 16x32 grid
  gemm_k<false><<<dim3(16, 32), blk, 0, stream>>>(x, Wq, Wq, Qb, Qb, NH_ * HD_, H_, 16);
  // K+V projections fused: 8x32 grid (4 cols each)
  gemm_k<false><<<dim3(8, 32), blk, 0, stream>>>(x, Wk, Wv, Kb, Vb, NKV_ * HD_, H_, 4);

  int rope_threads = M_ * (NH_ + NKV_) * 64;
  rope_k<<<dim3((rope_threads + 255) / 256), blk, 0, stream>>>(Qb, Kb, cosT, sinT);

  transp_v<<<dim3(M_ / 64, (NKV_ * HD_) / 64), blk, 0, stream>>>(Vb, VT);

  attn<<<dim3(S_ / 64, NH_, B_), blk, 0, stream>>>(Qb, Kb, VT, Qb);

  // Output projection: A = ctx (bf16, in Qb), C = out (f32)
  gemm_k<true><<<dim3(16, 32), blk, 0, stream>>>(Qb, Wo, Wo, out, out, H_, NH_ * HD_, 16);
}